// Round 9
// baseline (179.955 us; speedup 1.0000x reference)
//
#include <hip/hip_runtime.h>
#include <math.h>
#include <stdint.h>

// Problem constants (B,C,H,W) = (16,20,256,256), fp32 in, 4 fp32 scalars out.
constexpr int Bn = 16, Cn = 20, Hn = 256, Wn = 256;
constexpr int BCn = Bn * Cn;                 // 320 slices
constexpr int HWn = Hn * Wn;                 // 65536 per slice
constexpr int SPLIT = 4;                     // blocks per slice
constexpr int NBLK = BCn * SPLIT;            // 1280 blocks = exactly 5/CU
constexpr int CHUNK = HWn / SPLIT;           // 16384 elems per block
constexpr int TPB = 256;
constexpr int ITERS = CHUNK / (TPB * 4);     // 16 float4 per thread
constexpr int NSLOT = 10;
// ws layout TRANSPOSED: ws[slot * NBLK + blk]  (needs NSLOT*NBLK*4 = 51.2 KB)
// slots: 0 mass, 1 sum(t*y), 2 sum(t*x), 3 sum(p), 4 sum(p*y), 5 sum(p*x),
//        6 sum(p*(y^2+x^2)), 7 SUM(at*om^2*log2(pt)) [x ln2, negated in finalize],
//        8 (pred-t)^2, 9 |pred|
//
// R8 post-mortem: depth-4 NT = +1.5 us only -> MLP never binding in NT regime.
// Session evidence: normal loads pin at 2.4-2.65 TB/s (L2/L3 lookup path,
// invariant to occupancy/depth/warmth); NT loads pin at ~3.4 TB/s
// (read-around path, depth-invariant). Each pin was measured carrying 100%
// of traffic. External known-goods (fill 6.7 TB/s write-only, copy 3.15r+3.15w
// concurrent) say the fabric supports far more than 3.4 TB/s -> no structural
// arithmetic exists for a 3.4 wall. THIS ROUND's single variable: route the
// stream 50/50 across BOTH paths (slots 0/1 NT, slots 2/3 normal). If the
// paths queue independently -> bound by the L3 half: 84MB/2.5 ~ 34 us. If the
// bottleneck is shared (CU->fabric request ring) -> no change, and that IS the
// roofline proof.

typedef float f32x4 __attribute__((ext_vector_type(4)));

__device__ inline float wave_reduce(float v) {
    #pragma unroll
    for (int o = 32; o > 0; o >>= 1) v += __shfl_down(v, o, 64);
    return v;
}

__global__ __launch_bounds__(TPB) void partials_kernel(
        const float* __restrict__ pred, const float* __restrict__ target,
        float* __restrict__ ws) {
    const int blk = blockIdx.x;
    const int bc = blk >> 2;                 // / SPLIT
    const int chunk = blk & (SPLIT - 1);
    const long long base = (long long)bc * HWn + (long long)chunk * CHUNK;
    const f32x4* __restrict__ p4 = (const f32x4*)(pred + base);
    const f32x4* __restrict__ t4 = (const f32x4*)(target + base);
    const int tid = threadIdx.x;

    // Element e = chunk*CHUNK + i*1024 + tid*4 + j:
    //   x = (tid*4 & 255) + j   (iteration-invariant per lane)
    //   y = chunk*64 + i*4 + (tid>>6)
    const float x0 = (float)((tid * 4) & 255);
    float yf = (float)(chunk * 64 + (tid >> 6));
    constexpr float L2E = 1.44269504088896f; // log2(e)

    float a_mass = 0.f, a_ty = 0.f, a_jt = 0.f, a_p = 0.f, a_py = 0.f,
          a_jp = 0.f, a_pyy = 0.f, a_j2p = 0.f, a_foc = 0.f, a_sq = 0.f,
          a_abs = 0.f;

    auto PROC = [&](const f32x4& pc, const f32x4& tc) {
        const float pv4[4] = {pc.x, pc.y, pc.z, pc.w};
        const float tv4[4] = {tc.x, tc.y, tc.z, tc.w};
        float st4 = 0.f, sp4 = 0.f;
        #pragma unroll
        for (int j = 0; j < 4; j++) {
            const float v = pv4[j];
            const float t = tv4[j];          // exactly 0.0 or 1.0
            // sigmoid + focal in log2 domain (ln2 applied once in finalize):
            // u = v*log2(e); 1-p = e^{-v}*p -> log2(pt) = log2(p) - (1-t)*u
            const float u  = v * L2E;
            const float e  = __builtin_amdgcn_exp2f(-u);
            const float p  = __builtin_amdgcn_rcpf(1.0f + e);   // sigmoid
            const float l2p = __builtin_amdgcn_logf(p);         // log2(p)
            const float l2pt = fmaf(t, u, l2p - u);
            const float om = fmaf(t, fmaf(p, -2.0f, 1.0f), p);  // 1 - pt
            const float at = fmaf(t, -0.5f, 0.75f);             // alpha_t
            a_foc = fmaf(at * l2pt, om * om, a_foc);
            const float d = v - t;
            a_sq = fmaf(d, d, a_sq);
            a_abs += fabsf(v);
            st4 += t;
            sp4 += p;
            if (j == 1)      { a_jt += t;                 a_jp += p;                 a_j2p += p; }
            else if (j == 2) { a_jt = fmaf(t, 2.f, a_jt); a_jp = fmaf(p, 2.f, a_jp); a_j2p = fmaf(p, 4.f, a_j2p); }
            else if (j == 3) { a_jt = fmaf(t, 3.f, a_jt); a_jp = fmaf(p, 3.f, a_jp); a_j2p = fmaf(p, 9.f, a_j2p); }
        }
        a_mass += st4;
        a_ty  = fmaf(st4, yf, a_ty);
        a_p   += sp4;
        a_py  = fmaf(sp4, yf, a_py);
        a_pyy = fmaf(sp4, yf * yf, a_pyy);
        yf += 4.0f;                          // next iteration is 4 rows down
    };

    // ---- depth-4 pipeline, dual-path: slots 0/1 NT (read-around / HBM path),
    // ---- slots 2/3 normal (L2/L3 lookup path). 50/50 deterministic split.
    f32x4 P0 = __builtin_nontemporal_load(p4 + 0 * TPB + tid);
    f32x4 T0 = __builtin_nontemporal_load(t4 + 0 * TPB + tid);
    f32x4 P1 = __builtin_nontemporal_load(p4 + 1 * TPB + tid);
    f32x4 T1 = __builtin_nontemporal_load(t4 + 1 * TPB + tid);
    f32x4 P2 = p4[2 * TPB + tid];
    f32x4 T2 = t4[2 * TPB + tid];
    f32x4 P3 = p4[3 * TPB + tid];
    f32x4 T3 = t4[3 * TPB + tid];

    int i = 0;
    #pragma unroll 1
    for (; i + 4 < ITERS; i += 4) {          // i = 0, 4, 8  (3 trips)
        PROC(P0, T0);
        P0 = __builtin_nontemporal_load(p4 + (i + 4) * TPB + tid);
        T0 = __builtin_nontemporal_load(t4 + (i + 4) * TPB + tid);
        PROC(P1, T1);
        P1 = __builtin_nontemporal_load(p4 + (i + 5) * TPB + tid);
        T1 = __builtin_nontemporal_load(t4 + (i + 5) * TPB + tid);
        PROC(P2, T2);
        P2 = p4[(i + 6) * TPB + tid];
        T2 = t4[(i + 6) * TPB + tid];
        PROC(P3, T3);
        P3 = p4[(i + 7) * TPB + tid];
        T3 = t4[(i + 7) * TPB + tid];
    }
    PROC(P0, T0); PROC(P1, T1); PROC(P2, T2); PROC(P3, T3);   // drain

    // Fold lane-constant x moments: x = x0 + j
    float slot[NSLOT];
    slot[0] = a_mass;
    slot[1] = a_ty;
    slot[2] = fmaf(x0, a_mass, a_jt);                         // sum t*x
    slot[3] = a_p;
    slot[4] = a_py;
    slot[5] = fmaf(x0, a_p, a_jp);                            // sum p*x
    slot[6] = a_pyy + x0 * x0 * a_p + 2.f * x0 * a_jp + a_j2p;// sum p*(y^2+x^2)
    slot[7] = a_foc;
    slot[8] = a_sq;
    slot[9] = a_abs;

    __shared__ float red[TPB / 64][NSLOT];
    const int lane = tid & 63, wave = tid >> 6;
    #pragma unroll
    for (int k = 0; k < NSLOT; k++) {
        const float r = wave_reduce(slot[k]);
        if (lane == 0) red[wave][k] = r;
    }
    __syncthreads();
    if (tid < NSLOT) {
        float s = 0.f;
        #pragma unroll
        for (int w = 0; w < TPB / 64; w++) s += red[w][tid];
        ws[tid * NBLK + blk] = s;            // transposed store
    }
}

// 320 threads: thread tid owns slice (b,c)=tid. With SPLIT=4 and transposed ws,
// each slot's 4 partials for a slice are exactly one float4 -> 10 vector loads.
__global__ __launch_bounds__(320) void finalize_kernel(
        const float* __restrict__ ws, float* __restrict__ out) {
    const int tid = threadIdx.x;
    const float4* __restrict__ w4 = (const float4*)ws;

    float s[NSLOT];
    #pragma unroll
    for (int k = 0; k < NSLOT; k++) {
        const float4 v = w4[k * (NBLK / 4) + tid];
        s[k] = v.x + v.y + v.z + v.w;
    }

    // ---- per-(b,c) concentration term ----
    const float mass = s[0];
    const bool valid = mass > 0.f;
    const float sm = valid ? mass : 1.0f;
    const float cy = s[1] / sm, cx = s[2] / sm;
    const float pdsq = s[6] - 2.f * cy * s[4] - 2.f * cx * s[5]
                     + (cy * cy + cx * cx) * s[3];
    float vals[5];
    vals[0] = valid ? (pdsq / (float)HWn) : 0.f;   // conc per-sample mean
    vals[1] = valid ? 1.f : 0.f;                   // n_valid
    vals[2] = s[7];                                // focal sum (log2 domain)
    vals[3] = s[8];                                // sum (pred-t)^2
    vals[4] = s[9];                                // sum |pred|

    __shared__ float lds[5][5];
    const int lane = tid & 63, wave = tid >> 6;
    #pragma unroll
    for (int k = 0; k < 5; k++) {
        const float r = wave_reduce(vals[k]);
        if (lane == 0) lds[wave][k] = r;
    }
    __syncthreads();

    if (tid == 0) {
        float tot[5];
        #pragma unroll
        for (int k = 0; k < 5; k++) {
            float a = 0.f;
            #pragma unroll
            for (int w = 0; w < 5; w++) a += lds[w][k];
            tot[k] = a;
        }
        const float NTOT = (float)Bn * Cn * Hn * Wn;   // 20971520
        constexpr float LN2 = 0.69314718055994531f;
        const float focal = -LN2 * tot[2] / NTOT;      // restore ln from log2
        const float sparsity = tot[3] / NTOT + tot[4] / NTOT;
        const float concentration =
            (tot[1] > 0.f) ? (tot[0] / fmaxf(tot[1], 1.f)) : 0.f;
        const float total = 1.0f * focal + 0.8f * sparsity + 1.5f * concentration;
        out[0] = total;
        out[1] = focal;
        out[2] = sparsity;
        out[3] = concentration;
    }
}

extern "C" void kernel_launch(void* const* d_in, const int* in_sizes, int n_in,
                              void* d_out, int out_size, void* d_ws, size_t ws_size,
                              hipStream_t stream) {
    const float* pred   = (const float*)d_in[0];
    const float* target = (const float*)d_in[1];
    float* out = (float*)d_out;
    float* ws  = (float*)d_ws;   // needs NSLOT*NBLK*4 = 51.2 KB

    partials_kernel<<<NBLK, TPB, 0, stream>>>(pred, target, ws);
    finalize_kernel<<<1, 320, 0, stream>>>(ws, out);
}

// Round 10
// 168.651 us; speedup vs baseline: 1.0670x; 1.0670x over previous
//
#include <hip/hip_runtime.h>
#include <math.h>
#include <stdint.h>

// Problem constants (B,C,H,W) = (16,20,256,256), fp32 in, 4 fp32 scalars out.
constexpr int Bn = 16, Cn = 20, Hn = 256, Wn = 256;
constexpr int BCn = Bn * Cn;                 // 320 slices
constexpr int HWn = Hn * Wn;                 // 65536 per slice
constexpr int SPLIT = 4;                     // blocks per slice
constexpr int NBLK = BCn * SPLIT;            // 1280 blocks = exactly 5/CU
constexpr int CHUNK = HWn / SPLIT;           // 16384 elems per block
constexpr int TPB = 256;
constexpr int ITERS = CHUNK / (TPB * 4);     // 16 float4 per thread
constexpr int NSLOT = 10;
// ws layout TRANSPOSED: ws[slot * NBLK + blk]  (needs NSLOT*NBLK*4 = 51.2 KB)
// slots: 0 mass, 1 sum(t*y), 2 sum(t*x), 3 sum(p), 4 sum(p*y), 5 sum(p*x),
//        6 sum(p*(y^2+x^2)), 7 SUM(at*om^2*log2(pt)) [x ln2, negated in finalize],
//        8 (pred-t)^2, 9 |pred|
//
// FINAL (R10 = revert to R8, the session best at 170.9 us total).
// Session conclusion: the partials kernel is READ-PATH BOUND at ~3.4 TB/s.
//   - normal loads pin at 2.4-2.65 TB/s (L2/L3 lookup path) regardless of
//     occupancy (22-65%), MLP depth (1-6), VGPR vs LDS-DMA payload, phase,
//     or L3 warmth (warm == cold).
//   - NT loads (read-around) pin at ~3.4 TB/s, depth-invariant.
//   - 50/50 dual-path split (R9): 3.17 TB/s, NO additivity -> shared limiter.
//   - External known-goods: m13 copy reads 3.15 TB/s (while writing 3.15);
//     fill writes 6.7 TB/s. Our 3.4 TB/s read EXCEEDS the best demonstrated
//     read rate on this chip.
// Floor arithmetic: 168 MB / 3.4 TB/s ~ 49 us = measured partials (49-51 us).
// Remaining total is finalize (~5 us) + harness re-poison fills (~117 us,
// not kernel-addressable). This is the roofline.

typedef float f32x4 __attribute__((ext_vector_type(4)));

__device__ inline float wave_reduce(float v) {
    #pragma unroll
    for (int o = 32; o > 0; o >>= 1) v += __shfl_down(v, o, 64);
    return v;
}

__global__ __launch_bounds__(TPB) void partials_kernel(
        const float* __restrict__ pred, const float* __restrict__ target,
        float* __restrict__ ws) {
    const int blk = blockIdx.x;
    const int bc = blk >> 2;                 // / SPLIT
    const int chunk = blk & (SPLIT - 1);
    const long long base = (long long)bc * HWn + (long long)chunk * CHUNK;
    const f32x4* __restrict__ p4 = (const f32x4*)(pred + base);
    const f32x4* __restrict__ t4 = (const f32x4*)(target + base);
    const int tid = threadIdx.x;

    // Element e = chunk*CHUNK + i*1024 + tid*4 + j:
    //   x = (tid*4 & 255) + j   (iteration-invariant per lane)
    //   y = chunk*64 + i*4 + (tid>>6)
    const float x0 = (float)((tid * 4) & 255);
    float yf = (float)(chunk * 64 + (tid >> 6));
    constexpr float L2E = 1.44269504088896f; // log2(e)

    float a_mass = 0.f, a_ty = 0.f, a_jt = 0.f, a_p = 0.f, a_py = 0.f,
          a_jp = 0.f, a_pyy = 0.f, a_j2p = 0.f, a_foc = 0.f, a_sq = 0.f,
          a_abs = 0.f;

    auto PROC = [&](const f32x4& pc, const f32x4& tc) {
        const float pv4[4] = {pc.x, pc.y, pc.z, pc.w};
        const float tv4[4] = {tc.x, tc.y, tc.z, tc.w};
        float st4 = 0.f, sp4 = 0.f;
        #pragma unroll
        for (int j = 0; j < 4; j++) {
            const float v = pv4[j];
            const float t = tv4[j];          // exactly 0.0 or 1.0
            // sigmoid + focal in log2 domain (ln2 applied once in finalize):
            // u = v*log2(e); 1-p = e^{-v}*p -> log2(pt) = log2(p) - (1-t)*u
            const float u  = v * L2E;
            const float e  = __builtin_amdgcn_exp2f(-u);
            const float p  = __builtin_amdgcn_rcpf(1.0f + e);   // sigmoid
            const float l2p = __builtin_amdgcn_logf(p);         // log2(p)
            const float l2pt = fmaf(t, u, l2p - u);
            const float om = fmaf(t, fmaf(p, -2.0f, 1.0f), p);  // 1 - pt
            const float at = fmaf(t, -0.5f, 0.75f);             // alpha_t
            a_foc = fmaf(at * l2pt, om * om, a_foc);
            const float d = v - t;
            a_sq = fmaf(d, d, a_sq);
            a_abs += fabsf(v);
            st4 += t;
            sp4 += p;
            if (j == 1)      { a_jt += t;                 a_jp += p;                 a_j2p += p; }
            else if (j == 2) { a_jt = fmaf(t, 2.f, a_jt); a_jp = fmaf(p, 2.f, a_jp); a_j2p = fmaf(p, 4.f, a_j2p); }
            else if (j == 3) { a_jt = fmaf(t, 3.f, a_jt); a_jp = fmaf(p, 3.f, a_jp); a_j2p = fmaf(p, 9.f, a_j2p); }
        }
        a_mass += st4;
        a_ty  = fmaf(st4, yf, a_ty);
        a_p   += sp4;
        a_py  = fmaf(sp4, yf, a_py);
        a_pyy = fmaf(sp4, yf * yf, a_pyy);
        yf += 4.0f;                          // next iteration is 4 rows down
    };

    // ---- depth-4 NT software pipeline ----
    f32x4 P0 = __builtin_nontemporal_load(p4 + 0 * TPB + tid);
    f32x4 T0 = __builtin_nontemporal_load(t4 + 0 * TPB + tid);
    f32x4 P1 = __builtin_nontemporal_load(p4 + 1 * TPB + tid);
    f32x4 T1 = __builtin_nontemporal_load(t4 + 1 * TPB + tid);
    f32x4 P2 = __builtin_nontemporal_load(p4 + 2 * TPB + tid);
    f32x4 T2 = __builtin_nontemporal_load(t4 + 2 * TPB + tid);
    f32x4 P3 = __builtin_nontemporal_load(p4 + 3 * TPB + tid);
    f32x4 T3 = __builtin_nontemporal_load(t4 + 3 * TPB + tid);

    int i = 0;
    #pragma unroll 1
    for (; i + 4 < ITERS; i += 4) {          // i = 0, 4, 8  (3 trips)
        PROC(P0, T0);
        P0 = __builtin_nontemporal_load(p4 + (i + 4) * TPB + tid);
        T0 = __builtin_nontemporal_load(t4 + (i + 4) * TPB + tid);
        PROC(P1, T1);
        P1 = __builtin_nontemporal_load(p4 + (i + 5) * TPB + tid);
        T1 = __builtin_nontemporal_load(t4 + (i + 5) * TPB + tid);
        PROC(P2, T2);
        P2 = __builtin_nontemporal_load(p4 + (i + 6) * TPB + tid);
        T2 = __builtin_nontemporal_load(t4 + (i + 6) * TPB + tid);
        PROC(P3, T3);
        P3 = __builtin_nontemporal_load(p4 + (i + 7) * TPB + tid);
        T3 = __builtin_nontemporal_load(t4 + (i + 7) * TPB + tid);
    }
    PROC(P0, T0); PROC(P1, T1); PROC(P2, T2); PROC(P3, T3);   // drain

    // Fold lane-constant x moments: x = x0 + j
    float slot[NSLOT];
    slot[0] = a_mass;
    slot[1] = a_ty;
    slot[2] = fmaf(x0, a_mass, a_jt);                         // sum t*x
    slot[3] = a_p;
    slot[4] = a_py;
    slot[5] = fmaf(x0, a_p, a_jp);                            // sum p*x
    slot[6] = a_pyy + x0 * x0 * a_p + 2.f * x0 * a_jp + a_j2p;// sum p*(y^2+x^2)
    slot[7] = a_foc;
    slot[8] = a_sq;
    slot[9] = a_abs;

    __shared__ float red[TPB / 64][NSLOT];
    const int lane = tid & 63, wave = tid >> 6;
    #pragma unroll
    for (int k = 0; k < NSLOT; k++) {
        const float r = wave_reduce(slot[k]);
        if (lane == 0) red[wave][k] = r;
    }
    __syncthreads();
    if (tid < NSLOT) {
        float s = 0.f;
        #pragma unroll
        for (int w = 0; w < TPB / 64; w++) s += red[w][tid];
        ws[tid * NBLK + blk] = s;            // transposed store
    }
}

// 320 threads: thread tid owns slice (b,c)=tid. With SPLIT=4 and transposed ws,
// each slot's 4 partials for a slice are exactly one float4 -> 10 vector loads.
__global__ __launch_bounds__(320) void finalize_kernel(
        const float* __restrict__ ws, float* __restrict__ out) {
    const int tid = threadIdx.x;
    const float4* __restrict__ w4 = (const float4*)ws;

    float s[NSLOT];
    #pragma unroll
    for (int k = 0; k < NSLOT; k++) {
        const float4 v = w4[k * (NBLK / 4) + tid];
        s[k] = v.x + v.y + v.z + v.w;
    }

    // ---- per-(b,c) concentration term ----
    const float mass = s[0];
    const bool valid = mass > 0.f;
    const float sm = valid ? mass : 1.0f;
    const float cy = s[1] / sm, cx = s[2] / sm;
    const float pdsq = s[6] - 2.f * cy * s[4] - 2.f * cx * s[5]
                     + (cy * cy + cx * cx) * s[3];
    float vals[5];
    vals[0] = valid ? (pdsq / (float)HWn) : 0.f;   // conc per-sample mean
    vals[1] = valid ? 1.f : 0.f;                   // n_valid
    vals[2] = s[7];                                // focal sum (log2 domain)
    vals[3] = s[8];                                // sum (pred-t)^2
    vals[4] = s[9];                                // sum |pred|

    __shared__ float lds[5][5];
    const int lane = tid & 63, wave = tid >> 6;
    #pragma unroll
    for (int k = 0; k < 5; k++) {
        const float r = wave_reduce(vals[k]);
        if (lane == 0) lds[wave][k] = r;
    }
    __syncthreads();

    if (tid == 0) {
        float tot[5];
        #pragma unroll
        for (int k = 0; k < 5; k++) {
            float a = 0.f;
            #pragma unroll
            for (int w = 0; w < 5; w++) a += lds[w][k];
            tot[k] = a;
        }
        const float NTOT = (float)Bn * Cn * Hn * Wn;   // 20971520
        constexpr float LN2 = 0.69314718055994531f;
        const float focal = -LN2 * tot[2] / NTOT;      // restore ln from log2
        const float sparsity = tot[3] / NTOT + tot[4] / NTOT;
        const float concentration =
            (tot[1] > 0.f) ? (tot[0] / fmaxf(tot[1], 1.f)) : 0.f;
        const float total = 1.0f * focal + 0.8f * sparsity + 1.5f * concentration;
        out[0] = total;
        out[1] = focal;
        out[2] = sparsity;
        out[3] = concentration;
    }
}

extern "C" void kernel_launch(void* const* d_in, const int* in_sizes, int n_in,
                              void* d_out, int out_size, void* d_ws, size_t ws_size,
                              hipStream_t stream) {
    const float* pred   = (const float*)d_in[0];
    const float* target = (const float*)d_in[1];
    float* out = (float*)d_out;
    float* ws  = (float*)d_ws;   // needs NSLOT*NBLK*4 = 51.2 KB

    partials_kernel<<<NBLK, TPB, 0, stream>>>(pred, target, ws);
    finalize_kernel<<<1, 320, 0, stream>>>(ws, out);
}